// Round 2
// baseline (79387.744 us; speedup 1.0000x reference)
//
#include <hip/hip_runtime.h>
#include <math.h>

#define T_LEN 1000
#define BATCH 16
#define MEL   80
#define HID   512
#define NCLS  64
#define SL    8        // slices (blocks) per chain
#define COLS  64       // columns per block

__device__ __forceinline__ float fast_tanh(float x) {
    float e = __expf(2.0f * x);
    return 1.0f - 2.0f / (e + 1.0f);
}
__device__ __forceinline__ float fast_sigmoid(float x) {
    return 1.0f / (1.0f + __expf(-x));
}

// ---- per-chain multi-block barrier (8 blocks, sense-reversing, agent scope)
__device__ __forceinline__ void chain_barrier(int* cnt, int* gen) {
    __syncthreads();
    __threadfence();   // release: h_buf/err_buf/S2 writes visible device-wide
    if (threadIdx.x == 0) {
        int g = __hip_atomic_load(gen, __ATOMIC_RELAXED, __HIP_MEMORY_SCOPE_AGENT);
        int old = __hip_atomic_fetch_add(cnt, 1, __ATOMIC_ACQ_REL, __HIP_MEMORY_SCOPE_AGENT);
        if (old == SL - 1) {
            // reset count BEFORE releasing waiters (release on gen publishes it)
            __hip_atomic_store(cnt, 0, __ATOMIC_RELAXED, __HIP_MEMORY_SCOPE_AGENT);
            __hip_atomic_fetch_add(gen, 1, __ATOMIC_RELEASE, __HIP_MEMORY_SCOPE_AGENT);
        } else {
            while (__hip_atomic_load(gen, __ATOMIC_ACQUIRE, __HIP_MEMORY_SCOPE_AGENT) == g) {
                __builtin_amdgcn_s_sleep(1);
            }
        }
    }
    __syncthreads();
    __threadfence();   // acquire: invalidate L1 so fresh h_buf/err_buf is read
}

// K0: zero the inter-block communication state (stream-ordered before k3)
__global__ void k0_init(float* h_buf, float* S2, int* cnt, int* gen) {
    int i = blockIdx.x * 256 + threadIdx.x;
    if (i < BATCH * HID) h_buf[i] = 0.f;
    if (i < BATCH * 2) S2[i] = 0.f;
    if (i < BATCH) { cnt[i] = 0; gen[i] = 0; }
}

// K1: per t: x_norm0 from feats, be0 = x_norm0 @ B0^T
__global__ __launch_bounds__(256) void k1_be0(const float* __restrict__ feats,
                                              const float* __restrict__ B0,
                                              float* __restrict__ be0) {
    const int t = blockIdx.x;
    const int tid = threadIdx.x;
    __shared__ float xf[BATCH][MEL];
    __shared__ float sc[BATCH];
    for (int idx = tid; idx < BATCH * MEL; idx += 256) {
        int b = idx / MEL, m = idx % MEL;
        xf[b][m] = feats[b * (T_LEN * MEL) + t * MEL + m];
    }
    __syncthreads();
    if (tid < BATCH) {
        float ss = 0.f;
        for (int m = 0; m < MEL; ++m) { float v = xf[tid][m]; ss += v * v; }
        sc[tid] = fmaxf(sqrtf(ss), 1e-6f);
    }
    __syncthreads();
    for (int idx = tid; idx < BATCH * MEL; idx += 256) {
        int b = idx / MEL, m = idx % MEL;
        float v = xf[b][m] / sc[b];
        xf[b][m] = fminf(fmaxf(v, -1.f), 1.f);
    }
    __syncthreads();
    for (int j = tid; j < HID; j += 256) {
        float acc[BATCH];
        #pragma unroll
        for (int b = 0; b < BATCH; ++b) acc[b] = 0.f;
        const float* brow = B0 + j * MEL;
        for (int k = 0; k < MEL; k += 4) {
            float4 w = *(const float4*)(brow + k);
            #pragma unroll
            for (int b = 0; b < BATCH; ++b) {
                float4 xv = *(const float4*)(&xf[b][k]);
                acc[b] += w.x * xv.x + w.y * xv.y + w.z * xv.z + w.w * xv.w;
            }
        }
        #pragma unroll
        for (int b = 0; b < BATCH; ++b)
            be0[(t * BATCH + b) * HID + j] = acc[b];
    }
}

// K2: per t: x_norm1 from be0, be1 = x_norm1 @ B1^T, store xs1
__global__ __launch_bounds__(256) void k2_be1(const float* __restrict__ be0,
                                              const float* __restrict__ B1,
                                              float* __restrict__ be1,
                                              float* __restrict__ xs1) {
    const int t = blockIdx.x;
    const int tid = threadIdx.x;
    __shared__ float xn[BATCH][HID];
    __shared__ float sc[BATCH];
    __shared__ float psum[BATCH][16];
    for (int idx = tid; idx < BATCH * HID; idx += 256) {
        int b = idx >> 9, k = idx & 511;
        xn[b][k] = be0[(t * BATCH + b) * HID + k];
    }
    __syncthreads();
    {
        int b = tid >> 4, l = tid & 15;
        float ss = 0.f;
        for (int k = l; k < HID; k += 16) { float v = xn[b][k]; ss += v * v; }
        psum[b][l] = ss;
    }
    __syncthreads();
    if (tid < BATCH) {
        float ss = 0.f;
        #pragma unroll
        for (int l = 0; l < 16; ++l) ss += psum[tid][l];
        float s = fmaxf(sqrtf(ss), 1e-6f);
        sc[tid] = s;
        xs1[t * BATCH + tid] = s;
    }
    __syncthreads();
    for (int idx = tid; idx < BATCH * HID; idx += 256) {
        int b = idx >> 9, k = idx & 511;
        float v = xn[b][k] / sc[b];
        xn[b][k] = fminf(fmaxf(v, -1.f), 1.f);
    }
    __syncthreads();
    for (int j = tid; j < HID; j += 256) {
        float acc[BATCH];
        #pragma unroll
        for (int b = 0; b < BATCH; ++b) acc[b] = 0.f;
        const float* brow = B1 + j * HID;
        for (int k = 0; k < HID; k += 4) {
            float4 w = *(const float4*)(brow + k);
            #pragma unroll
            for (int b = 0; b < BATCH; ++b) {
                float4 xv = *(const float4*)(&xn[b][k]);
                acc[b] += w.x * xv.x + w.y * xv.y + w.z * xv.z + w.w * xv.w;
            }
        }
        #pragma unroll
        for (int b = 0; b < BATCH; ++b)
            be1[(t * BATCH + b) * HID + j] = acc[b];
    }
}

// K3: sequential recurrence, 8 blocks per chain, weights register-resident.
// blockIdx = chain + 16*slice  (chain's blocks land on one XCD round-robin)
// thread: col = tid>>3 (0..63), ks = tid&7; k-chunks = ks + 8*i, i=0..15
__global__ __launch_bounds__(512, 2) void k3_coop(
    const float* __restrict__ be0, const float* __restrict__ be1,
    const float* __restrict__ xs1,
    const float* __restrict__ C1, const float* __restrict__ W1,
    const float* __restrict__ a1, const float* __restrict__ tau,
    const float* __restrict__ gam,
    float* __restrict__ h1s,
    float* h_buf, float* err_buf, float* S2, int* bar_cnt, int* bar_gen)
{
    const int chain = blockIdx.x & 15;
    const int slice = blockIdx.x >> 4;
    const int tid = threadIdx.x;
    const int col = tid >> 3;
    const int ks  = tid & 7;
    const int j   = slice * COLS + col;
    const bool lead = (ks == 0);

    __shared__ float h_s[HID];
    __shared__ float err_s[HID];
    __shared__ float red[8];

    // weights: 32 float4 = 128 VGPRs, loaded once, register-resident
    float4 wC[16], wW[16];
    {
        const float4* c4 = (const float4*)(C1 + (size_t)j * HID);
        const float4* w4 = (const float4*)(W1 + (size_t)j * HID);
        #pragma unroll
        for (int i = 0; i < 16; ++i) {
            wC[i] = c4[ks + 8 * i];
            wW[i] = w4[ks + 8 * i];
        }
    }
    const float tauv = tau[0], gamv = gam[0];
    const float siga = fast_sigmoid(a1[j]);
    float hj = 0.f;

    float* hb = h_buf + chain * HID;
    float* eb = err_buf + chain * HID;
    float* Sc = S2 + chain * 2;
    int* cnt = bar_cnt + chain;
    int* gen = bar_gen + chain;

    // prefetch t=0 streams
    float cur_be0 = 0.f, cur_be1 = 0.f;
    if (lead) {
        cur_be0 = be0[(size_t)(0 * BATCH + chain) * HID + j];
        cur_be1 = be1[(size_t)(0 * BATCH + chain) * HID + j];
    }
    float cur_xs = xs1[chain];

    for (int t = 0; t < T_LEN; ++t) {
        // software prefetch of next step's streams (latency off critical path)
        float nxt_be0 = 0.f, nxt_be1 = 0.f, nxt_xs = 0.f;
        if (t + 1 < T_LEN) {
            if (lead) {
                nxt_be0 = be0[(size_t)((t + 1) * BATCH + chain) * HID + j];
                nxt_be1 = be1[(size_t)((t + 1) * BATCH + chain) * HID + j];
            }
            nxt_xs = xs1[(t + 1) * BATCH + chain];
        }

        // ---- err phase: dp = (h @ C1^T)[j], e = be0 - tanh(dp)*xs ----
        h_s[tid] = hb[tid];
        __syncthreads();
        const float4* h4 = (const float4*)h_s;
        float dp = 0.f;
        #pragma unroll
        for (int i = 0; i < 16; ++i) {
            float4 h = h4[ks + 8 * i];   // 8 distinct contig float4/wave: 32 banks, bcast
            dp += wC[i].x * h.x + wC[i].y * h.y + wC[i].z * h.z + wC[i].w * h.w;
        }
        dp += __shfl_down(dp, 4, 8);
        dp += __shfl_down(dp, 2, 8);
        dp += __shfl_down(dp, 1, 8);
        float ssp = 0.f;
        if (lead) {
            float p = fast_tanh(dp);
            float e = cur_be0 - p * cur_xs;
            eb[j] = e;
            ssp = e * e;
        }
        #pragma unroll
        for (int off = 32; off > 0; off >>= 1) ssp += __shfl_down(ssp, off, 64);
        if ((tid & 63) == 0) red[tid >> 6] = ssp;
        __syncthreads();
        if (tid == 0) {
            float ss = ((red[0] + red[1]) + (red[2] + red[3]))
                     + ((red[4] + red[5]) + (red[6] + red[7]));
            atomicAdd(&Sc[t & 1], ss);   // device-scope
        }
        chain_barrier(cnt, gen);   // B1: err_buf + sumsq complete

        // ---- update phase: ee = (err @ W1^T)[j], gated h update ----
        err_s[tid] = eb[tid];
        float ssT = Sc[t & 1];
        if (slice == 0 && tid == 0)
            __hip_atomic_store(&Sc[(t + 1) & 1], 0.f, __ATOMIC_RELAXED,
                               __HIP_MEMORY_SCOPE_AGENT);  // recycle other slot
        __syncthreads();
        float rel = fminf(sqrtf(ssT) / cur_xs, 4.0f);
        float s = fast_sigmoid((rel - tauv) / gamv);
        const float4* e4 = (const float4*)err_s;
        float ee = 0.f;
        #pragma unroll
        for (int i = 0; i < 16; ++i) {
            float4 ev = e4[ks + 8 * i];
            ee += wW[i].x * ev.x + wW[i].y * ev.y + wW[i].z * ev.z + wW[i].w * ev.w;
        }
        ee += __shfl_down(ee, 4, 8);
        ee += __shfl_down(ee, 2, 8);
        ee += __shfl_down(ee, 1, 8);
        if (lead) {
            float input_h = hj * 0.2f + cur_be1 * 0.6f + ee * s * 0.2f;
            float g = s * siga;
            hj = hj * (1.f - g) + fast_tanh(input_h) * g;
            hb[j] = hj;
            h1s[(size_t)(t * BATCH + chain) * HID + j] = hj;
        }
        chain_barrier(cnt, gen);   // B2: h_buf complete for next step

        cur_be0 = nxt_be0; cur_be1 = nxt_be1; cur_xs = nxt_xs;
    }
}

// K4: head matmul out[b,t,c] = [h1 || be1] @ head_w^T + head_b
__global__ __launch_bounds__(1024) void k4_head(const float* __restrict__ h1s,
                                                const float* __restrict__ be1,
                                                const float* __restrict__ head_w,
                                                const float* __restrict__ head_b,
                                                float* __restrict__ out) {
    const int t = blockIdx.x;
    const int tid = threadIdx.x;
    const int c = tid >> 4;
    const int b = tid & 15;
    const float* hw = head_w + c * (2 * HID);
    const float* x1 = h1s + (size_t)(t * BATCH + b) * HID;
    const float* x2 = be1 + (size_t)(t * BATCH + b) * HID;
    float acc0 = head_b[c], acc1 = 0.f;
    for (int k = 0; k < HID; k += 4) {
        float4 w = *(const float4*)(hw + k);
        float4 xv = *(const float4*)(x1 + k);
        acc0 += w.x * xv.x + w.y * xv.y + w.z * xv.z + w.w * xv.w;
    }
    for (int k = 0; k < HID; k += 4) {
        float4 w = *(const float4*)(hw + HID + k);
        float4 xv = *(const float4*)(x2 + k);
        acc1 += w.x * xv.x + w.y * xv.y + w.z * xv.z + w.w * xv.w;
    }
    out[b * (T_LEN * NCLS) + t * NCLS + c] = acc0 + acc1;
}

extern "C" void kernel_launch(void* const* d_in, const int* in_sizes, int n_in,
                              void* d_out, int out_size, void* d_ws, size_t ws_size,
                              hipStream_t stream) {
    const float* feats  = (const float*)d_in[0];
    const float* B0     = (const float*)d_in[2];
    const float* C1     = (const float*)d_in[7];
    const float* B1     = (const float*)d_in[8];
    const float* W1     = (const float*)d_in[9];
    const float* a1     = (const float*)d_in[10];
    const float* tau1   = (const float*)d_in[11];
    const float* gam1   = (const float*)d_in[12];
    const float* head_w = (const float*)d_in[13];
    const float* head_b = (const float*)d_in[14];
    float* out = (float*)d_out;

    float* be0   = (float*)d_ws;                          // T*B*HID
    float* be1   = be0 + (size_t)T_LEN * BATCH * HID;     // T*B*HID
    float* xs1   = be1 + (size_t)T_LEN * BATCH * HID;     // T*B
    float* h1s   = xs1 + (size_t)T_LEN * BATCH;           // T*B*HID
    float* h_buf = h1s + (size_t)T_LEN * BATCH * HID;     // B*HID
    float* ebuf  = h_buf + (size_t)BATCH * HID;           // B*HID
    float* S2    = ebuf + (size_t)BATCH * HID;            // B*2
    int*   cnt   = (int*)(S2 + BATCH * 2);                // B
    int*   gen   = cnt + BATCH;                           // B

    hipLaunchKernelGGL(k0_init, dim3(32), dim3(256), 0, stream, h_buf, S2, cnt, gen);
    hipLaunchKernelGGL(k1_be0, dim3(T_LEN), dim3(256), 0, stream, feats, B0, be0);
    hipLaunchKernelGGL(k2_be1, dim3(T_LEN), dim3(256), 0, stream, be0, B1, be1, xs1);
    hipLaunchKernelGGL(k3_coop, dim3(BATCH * SL), dim3(512), 0, stream,
                       be0, be1, xs1, C1, W1, a1, tau1, gam1, h1s,
                       h_buf, ebuf, S2, cnt, gen);
    hipLaunchKernelGGL(k4_head, dim3(T_LEN), dim3(1024), 0, stream,
                       h1s, be1, head_w, head_b, out);
}

// Round 3
// 66498.279 us; speedup vs baseline: 1.1938x; 1.1938x over previous
//
#include <hip/hip_runtime.h>
#include <math.h>

#define T_LEN 1000
#define BATCH 16
#define MEL   80
#define HID   512
#define NCLS  64
#define SL    8        // column slices (blocks) per chain
#define NWAVE 64       // producing waves per chain (8 blocks x 8 waves)

__device__ __forceinline__ float fast_tanh(float x) {
    float e = __expf(2.0f * x);
    return 1.0f - 2.0f / (e + 1.0f);
}
__device__ __forceinline__ float fast_sigmoid(float x) {
    return 1.0f / (1.0f + __expf(-x));
}

// K0: zero inter-block state (h_buf, ssq, flags). Runs before k3 on stream.
__global__ void k0_init(float* h_buf, float* ssq, int* flags) {
    int i = blockIdx.x * 256 + threadIdx.x;
    if (i < BATCH * HID) h_buf[i] = 0.f;
    if (i < BATCH * NWAVE) { ssq[i] = 0.f; flags[i] = 0; }
}

// K1: per t: x_norm0 from feats, be0 = x_norm0 @ B0^T
__global__ __launch_bounds__(256) void k1_be0(const float* __restrict__ feats,
                                              const float* __restrict__ B0,
                                              float* __restrict__ be0) {
    const int t = blockIdx.x;
    const int tid = threadIdx.x;
    __shared__ float xf[BATCH][MEL];
    __shared__ float sc[BATCH];
    for (int idx = tid; idx < BATCH * MEL; idx += 256) {
        int b = idx / MEL, m = idx % MEL;
        xf[b][m] = feats[b * (T_LEN * MEL) + t * MEL + m];
    }
    __syncthreads();
    if (tid < BATCH) {
        float ss = 0.f;
        for (int m = 0; m < MEL; ++m) { float v = xf[tid][m]; ss += v * v; }
        sc[tid] = fmaxf(sqrtf(ss), 1e-6f);
    }
    __syncthreads();
    for (int idx = tid; idx < BATCH * MEL; idx += 256) {
        int b = idx / MEL, m = idx % MEL;
        float v = xf[b][m] / sc[b];
        xf[b][m] = fminf(fmaxf(v, -1.f), 1.f);
    }
    __syncthreads();
    for (int j = tid; j < HID; j += 256) {
        float acc[BATCH];
        #pragma unroll
        for (int b = 0; b < BATCH; ++b) acc[b] = 0.f;
        const float* brow = B0 + j * MEL;
        for (int k = 0; k < MEL; k += 4) {
            float4 w = *(const float4*)(brow + k);
            #pragma unroll
            for (int b = 0; b < BATCH; ++b) {
                float4 xv = *(const float4*)(&xf[b][k]);
                acc[b] += w.x * xv.x + w.y * xv.y + w.z * xv.z + w.w * xv.w;
            }
        }
        #pragma unroll
        for (int b = 0; b < BATCH; ++b)
            be0[(t * BATCH + b) * HID + j] = acc[b];
    }
}

// K2: per t: x_norm1 from be0, be1 = x_norm1 @ B1^T, store xs1
__global__ __launch_bounds__(256) void k2_be1(const float* __restrict__ be0,
                                              const float* __restrict__ B1,
                                              float* __restrict__ be1,
                                              float* __restrict__ xs1) {
    const int t = blockIdx.x;
    const int tid = threadIdx.x;
    __shared__ float xn[BATCH][HID];
    __shared__ float sc[BATCH];
    __shared__ float psum[BATCH][16];
    for (int idx = tid; idx < BATCH * HID; idx += 256) {
        int b = idx >> 9, k = idx & 511;
        xn[b][k] = be0[(t * BATCH + b) * HID + k];
    }
    __syncthreads();
    {
        int b = tid >> 4, l = tid & 15;
        float ss = 0.f;
        for (int k = l; k < HID; k += 16) { float v = xn[b][k]; ss += v * v; }
        psum[b][l] = ss;
    }
    __syncthreads();
    if (tid < BATCH) {
        float ss = 0.f;
        #pragma unroll
        for (int l = 0; l < 16; ++l) ss += psum[tid][l];
        float s = fmaxf(sqrtf(ss), 1e-6f);
        sc[tid] = s;
        xs1[t * BATCH + tid] = s;
    }
    __syncthreads();
    for (int idx = tid; idx < BATCH * HID; idx += 256) {
        int b = idx >> 9, k = idx & 511;
        float v = xn[b][k] / sc[b];
        xn[b][k] = fminf(fmaxf(v, -1.f), 1.f);
    }
    __syncthreads();
    for (int j = tid; j < HID; j += 256) {
        float acc[BATCH];
        #pragma unroll
        for (int b = 0; b < BATCH; ++b) acc[b] = 0.f;
        const float* brow = B1 + j * HID;
        for (int k = 0; k < HID; k += 4) {
            float4 w = *(const float4*)(brow + k);
            #pragma unroll
            for (int b = 0; b < BATCH; ++b) {
                float4 xv = *(const float4*)(&xn[b][k]);
                acc[b] += w.x * xv.x + w.y * xv.y + w.z * xv.z + w.w * xv.w;
            }
        }
        #pragma unroll
        for (int b = 0; b < BATCH; ++b)
            be1[(t * BATCH + b) * HID + j] = acc[b];
    }
}

// K3: sequential recurrence. 8 blocks/chain, 8 waves/block; each wave owns
// 8 output columns, weights register-resident, wave-granular flag sync.
// No __syncthreads, no atomic RMW, relaxed polls + 1 acq/rel fence per phase.
__global__ __launch_bounds__(512, 2) void k3_wave(
    const float* __restrict__ be0, const float* __restrict__ be1,
    const float* __restrict__ xs1,
    const float* __restrict__ C1, const float* __restrict__ W1,
    const float* __restrict__ a1, const float* __restrict__ tau,
    const float* __restrict__ gam,
    float* __restrict__ h1s,
    float* h_buf, float* err_buf, float* ssq, int* flags)
{
    const int chain = blockIdx.x & 15;
    const int slice = blockIdx.x >> 4;
    const int tid = threadIdx.x;
    const int w = tid >> 6;          // wave in block 0..7
    const int lane = tid & 63;
    const int ks = lane & 7;         // k-group within column
    const int colw = lane >> 3;      // column within wave 0..7
    const int gw = slice * 8 + w;    // global wave id within chain 0..63
    const int j = slice * 64 + w * 8 + colw;   // output column 0..511
    const bool lead = (ks == 0);

    // 128 weight floats per lane, loaded once, register-resident
    float4 wC[16], wW[16];
    {
        const float4* c4 = (const float4*)(C1 + (size_t)j * HID);
        const float4* w4 = (const float4*)(W1 + (size_t)j * HID);
        #pragma unroll
        for (int i = 0; i < 16; ++i) { wC[i] = c4[ks + 8 * i]; wW[i] = w4[ks + 8 * i]; }
    }
    const float tauv = tau[0], gamv = gam[0];
    const float siga = fast_sigmoid(a1[j]);

    float* hb = h_buf + chain * HID;
    float* eb = err_buf + chain * HID;
    float* sq = ssq + chain * NWAVE;
    int* flg = flags + chain * NWAVE;

    float hj = 0.f;
    float cur_be0 = 0.f, cur_be1 = 0.f;
    if (lead) {
        cur_be0 = __builtin_nontemporal_load(&be0[(size_t)chain * HID + j]);
        cur_be1 = __builtin_nontemporal_load(&be1[(size_t)chain * HID + j]);
    }
    float cur_xs = __builtin_nontemporal_load(&xs1[chain]);

    for (int t = 0; t < T_LEN; ++t) {
        // prefetch next step's streams (nt: no L2 allocation, lands in VGPRs)
        float nxt_be0 = 0.f, nxt_be1 = 0.f, nxt_xs = 0.f;
        if (t + 1 < T_LEN) {
            const size_t nrow = (size_t)((t + 1) * BATCH + chain) * HID;
            if (lead) {
                nxt_be0 = __builtin_nontemporal_load(&be0[nrow + j]);
                nxt_be1 = __builtin_nontemporal_load(&be1[nrow + j]);
            }
            nxt_xs = __builtin_nontemporal_load(&xs1[(t + 1) * BATCH + chain]);
        }

        // ---- wait: h(t) published by all 64 waves (token 2t) ----
        {
            const int tok = 2 * t;
            while (true) {
                int v = __hip_atomic_load(&flg[lane], __ATOMIC_RELAXED,
                                          __HIP_MEMORY_SCOPE_AGENT);
                if (__all(v >= tok)) break;
                __builtin_amdgcn_s_sleep(1);
            }
        }
        __builtin_amdgcn_fence(__ATOMIC_ACQUIRE, "agent");   // one buffer_inv

        // ---- phase 1: dp = (h @ C1^T)[j], publish err + ssq partial ----
        float4 hv[16];
        const float4* hb4 = (const float4*)hb;
        #pragma unroll
        for (int i = 0; i < 16; ++i) hv[i] = hb4[ks + 8 * i];
        float dp = 0.f;
        #pragma unroll
        for (int i = 0; i < 16; ++i)
            dp += wC[i].x * hv[i].x + wC[i].y * hv[i].y
                + wC[i].z * hv[i].z + wC[i].w * hv[i].w;
        dp += __shfl_down(dp, 4, 8);
        dp += __shfl_down(dp, 2, 8);
        dp += __shfl_down(dp, 1, 8);
        float ssp = 0.f;
        if (lead) {
            float e = cur_be0 - fast_tanh(dp) * cur_xs;
            __hip_atomic_store(&eb[j], e, __ATOMIC_RELAXED, __HIP_MEMORY_SCOPE_AGENT);
            ssp = e * e;
        }
        #pragma unroll
        for (int off = 32; off > 0; off >>= 1) ssp += __shfl_down(ssp, off, 64);
        if (lane == 0)
            __hip_atomic_store(&sq[gw], ssp, __ATOMIC_RELAXED, __HIP_MEMORY_SCOPE_AGENT);
        __builtin_amdgcn_fence(__ATOMIC_RELEASE, "agent");   // drain + wbl2 (tiny)
        if (lane == 0)
            __hip_atomic_store(&flg[gw], 2 * t + 1, __ATOMIC_RELAXED,
                               __HIP_MEMORY_SCOPE_AGENT);

        // ---- wait: err(t) published by all 64 waves (token 2t+1) ----
        {
            const int tok = 2 * t + 1;
            while (true) {
                int v = __hip_atomic_load(&flg[lane], __ATOMIC_RELAXED,
                                          __HIP_MEMORY_SCOPE_AGENT);
                if (__all(v >= tok)) break;
                __builtin_amdgcn_s_sleep(1);
            }
        }
        __builtin_amdgcn_fence(__ATOMIC_ACQUIRE, "agent");

        // ---- phase 2: surprise + ee = (err @ W1^T)[j], gated update ----
        float sqv = sq[lane];
        #pragma unroll
        for (int off = 32; off > 0; off >>= 1) sqv += __shfl_down(sqv, off, 64);
        float ssT = __shfl(sqv, 0, 64);
        float4 ev[16];
        const float4* eb4 = (const float4*)eb;
        #pragma unroll
        for (int i = 0; i < 16; ++i) ev[i] = eb4[ks + 8 * i];
        float ee = 0.f;
        #pragma unroll
        for (int i = 0; i < 16; ++i)
            ee += wW[i].x * ev[i].x + wW[i].y * ev[i].y
                + wW[i].z * ev[i].z + wW[i].w * ev[i].w;
        ee += __shfl_down(ee, 4, 8);
        ee += __shfl_down(ee, 2, 8);
        ee += __shfl_down(ee, 1, 8);
        if (lead) {
            float rel = fminf(sqrtf(ssT) / cur_xs, 4.0f);
            float s = fast_sigmoid((rel - tauv) / gamv);
            float input_h = hj * 0.2f + cur_be1 * 0.6f + ee * s * 0.2f;
            float g = s * siga;
            hj = hj * (1.f - g) + fast_tanh(input_h) * g;
            __hip_atomic_store(&hb[j], hj, __ATOMIC_RELAXED, __HIP_MEMORY_SCOPE_AGENT);
            __builtin_nontemporal_store(hj, &h1s[(size_t)(t * BATCH + chain) * HID + j]);
        }
        __builtin_amdgcn_fence(__ATOMIC_RELEASE, "agent");
        if (lane == 0)
            __hip_atomic_store(&flg[gw], 2 * t + 2, __ATOMIC_RELAXED,
                               __HIP_MEMORY_SCOPE_AGENT);

        cur_be0 = nxt_be0; cur_be1 = nxt_be1; cur_xs = nxt_xs;
    }
}

// K4: head matmul out[b,t,c] = [h1 || be1] @ head_w^T + head_b
__global__ __launch_bounds__(1024) void k4_head(const float* __restrict__ h1s,
                                                const float* __restrict__ be1,
                                                const float* __restrict__ head_w,
                                                const float* __restrict__ head_b,
                                                float* __restrict__ out) {
    const int t = blockIdx.x;
    const int tid = threadIdx.x;
    const int c = tid >> 4;
    const int b = tid & 15;
    const float* hw = head_w + c * (2 * HID);
    const float* x1 = h1s + (size_t)(t * BATCH + b) * HID;
    const float* x2 = be1 + (size_t)(t * BATCH + b) * HID;
    float acc0 = head_b[c], acc1 = 0.f;
    for (int k = 0; k < HID; k += 4) {
        float4 w = *(const float4*)(hw + k);
        float4 xv = *(const float4*)(x1 + k);
        acc0 += w.x * xv.x + w.y * xv.y + w.z * xv.z + w.w * xv.w;
    }
    for (int k = 0; k < HID; k += 4) {
        float4 w = *(const float4*)(hw + HID + k);
        float4 xv = *(const float4*)(x2 + k);
        acc1 += w.x * xv.x + w.y * xv.y + w.z * xv.z + w.w * xv.w;
    }
    out[b * (T_LEN * NCLS) + t * NCLS + c] = acc0 + acc1;
}

extern "C" void kernel_launch(void* const* d_in, const int* in_sizes, int n_in,
                              void* d_out, int out_size, void* d_ws, size_t ws_size,
                              hipStream_t stream) {
    const float* feats  = (const float*)d_in[0];
    const float* B0     = (const float*)d_in[2];
    const float* C1     = (const float*)d_in[7];
    const float* B1     = (const float*)d_in[8];
    const float* W1     = (const float*)d_in[9];
    const float* a1     = (const float*)d_in[10];
    const float* tau1   = (const float*)d_in[11];
    const float* gam1   = (const float*)d_in[12];
    const float* head_w = (const float*)d_in[13];
    const float* head_b = (const float*)d_in[14];
    float* out = (float*)d_out;

    float* be0   = (float*)d_ws;                          // T*B*HID
    float* be1   = be0 + (size_t)T_LEN * BATCH * HID;     // T*B*HID
    float* xs1   = be1 + (size_t)T_LEN * BATCH * HID;     // T*B
    float* h1s   = xs1 + (size_t)T_LEN * BATCH;           // T*B*HID
    float* h_buf = h1s + (size_t)T_LEN * BATCH * HID;     // B*HID
    float* ebuf  = h_buf + (size_t)BATCH * HID;           // B*HID
    float* ssq   = ebuf + (size_t)BATCH * HID;            // B*64
    int*   flags = (int*)(ssq + BATCH * NWAVE);           // B*64

    hipLaunchKernelGGL(k0_init, dim3(32), dim3(256), 0, stream, h_buf, ssq, flags);
    hipLaunchKernelGGL(k1_be0, dim3(T_LEN), dim3(256), 0, stream, feats, B0, be0);
    hipLaunchKernelGGL(k2_be1, dim3(T_LEN), dim3(256), 0, stream, be0, B1, be1, xs1);
    hipLaunchKernelGGL(k3_wave, dim3(BATCH * SL), dim3(512), 0, stream,
                       be0, be1, xs1, C1, W1, a1, tau1, gam1, h1s,
                       h_buf, ebuf, ssq, flags);
    hipLaunchKernelGGL(k4_head, dim3(T_LEN), dim3(1024), 0, stream,
                       h1s, be1, head_w, head_b, out);
}

// Round 4
// 12728.230 us; speedup vs baseline: 6.2371x; 5.2245x over previous
//
#include <hip/hip_runtime.h>
#include <math.h>

#define T_LEN 1000
#define BATCH 16
#define MEL   80
#define HID   512
#define NCLS  64
#define SL    16       // column slices (blocks) per chain
#define NWAVE 64       // waves per chain (16 blocks x 4 waves)

__device__ __forceinline__ float fast_tanh(float x) {
    float e = __expf(2.0f * x);
    return 1.0f - 2.0f / (e + 1.0f);
}
__device__ __forceinline__ float fast_sigmoid(float x) {
    return 1.0f / (1.0f + __expf(-x));
}

// ---- cache-bypassing (coherence-point) memory ops: sc0 sc1 => skip L1+L2,
// hit die-level Infinity Cache which is device-coherent. No fences needed.
__device__ __forceinline__ void llc_load16(const float* base, float4 (&r)[16]) {
    asm volatile(
        "global_load_dwordx4 %0, %16, off sc0 sc1\n\t"
        "global_load_dwordx4 %1, %16, off offset:128 sc0 sc1\n\t"
        "global_load_dwordx4 %2, %16, off offset:256 sc0 sc1\n\t"
        "global_load_dwordx4 %3, %16, off offset:384 sc0 sc1\n\t"
        "global_load_dwordx4 %4, %16, off offset:512 sc0 sc1\n\t"
        "global_load_dwordx4 %5, %16, off offset:640 sc0 sc1\n\t"
        "global_load_dwordx4 %6, %16, off offset:768 sc0 sc1\n\t"
        "global_load_dwordx4 %7, %16, off offset:896 sc0 sc1\n\t"
        "global_load_dwordx4 %8, %16, off offset:1024 sc0 sc1\n\t"
        "global_load_dwordx4 %9, %16, off offset:1152 sc0 sc1\n\t"
        "global_load_dwordx4 %10, %16, off offset:1280 sc0 sc1\n\t"
        "global_load_dwordx4 %11, %16, off offset:1408 sc0 sc1\n\t"
        "global_load_dwordx4 %12, %16, off offset:1536 sc0 sc1\n\t"
        "global_load_dwordx4 %13, %16, off offset:1664 sc0 sc1\n\t"
        "global_load_dwordx4 %14, %16, off offset:1792 sc0 sc1\n\t"
        "global_load_dwordx4 %15, %16, off offset:1920 sc0 sc1\n\t"
        "s_waitcnt vmcnt(0)"
        : "=&v"(r[0]), "=&v"(r[1]), "=&v"(r[2]), "=&v"(r[3]),
          "=&v"(r[4]), "=&v"(r[5]), "=&v"(r[6]), "=&v"(r[7]),
          "=&v"(r[8]), "=&v"(r[9]), "=&v"(r[10]), "=&v"(r[11]),
          "=&v"(r[12]), "=&v"(r[13]), "=&v"(r[14]), "=&v"(r[15])
        : "v"(base)
        : "memory");
}
__device__ __forceinline__ void llc_store_f32(float* p, float v) {
    asm volatile("global_store_dword %0, %1, off sc0 sc1" :: "v"(p), "v"(v) : "memory");
}
__device__ __forceinline__ void vm_drain() {
    asm volatile("s_waitcnt vmcnt(0)" ::: "memory");
}

// K0: zero inter-block state
__global__ void k0_init(float* h_buf, int* flags) {
    int i = blockIdx.x * 256 + threadIdx.x;
    if (i < BATCH * HID) h_buf[i] = 0.f;
    if (i < BATCH * NWAVE) flags[i] = 0;
}

// K1: per t: x_norm0 from feats, be0 = x_norm0 @ B0^T
__global__ __launch_bounds__(256) void k1_be0(const float* __restrict__ feats,
                                              const float* __restrict__ B0,
                                              float* __restrict__ be0) {
    const int t = blockIdx.x;
    const int tid = threadIdx.x;
    __shared__ float xf[BATCH][MEL];
    __shared__ float sc[BATCH];
    for (int idx = tid; idx < BATCH * MEL; idx += 256) {
        int b = idx / MEL, m = idx % MEL;
        xf[b][m] = feats[b * (T_LEN * MEL) + t * MEL + m];
    }
    __syncthreads();
    if (tid < BATCH) {
        float ss = 0.f;
        for (int m = 0; m < MEL; ++m) { float v = xf[tid][m]; ss += v * v; }
        sc[tid] = fmaxf(sqrtf(ss), 1e-6f);
    }
    __syncthreads();
    for (int idx = tid; idx < BATCH * MEL; idx += 256) {
        int b = idx / MEL, m = idx % MEL;
        float v = xf[b][m] / sc[b];
        xf[b][m] = fminf(fmaxf(v, -1.f), 1.f);
    }
    __syncthreads();
    for (int j = tid; j < HID; j += 256) {
        float acc[BATCH];
        #pragma unroll
        for (int b = 0; b < BATCH; ++b) acc[b] = 0.f;
        const float* brow = B0 + j * MEL;
        for (int k = 0; k < MEL; k += 4) {
            float4 w = *(const float4*)(brow + k);
            #pragma unroll
            for (int b = 0; b < BATCH; ++b) {
                float4 xv = *(const float4*)(&xf[b][k]);
                acc[b] += w.x * xv.x + w.y * xv.y + w.z * xv.z + w.w * xv.w;
            }
        }
        #pragma unroll
        for (int b = 0; b < BATCH; ++b)
            be0[(t * BATCH + b) * HID + j] = acc[b];
    }
}

// K2: per t: x_norm1 from be0, be1 = x_norm1 @ B1^T, store xs1
__global__ __launch_bounds__(256) void k2_be1(const float* __restrict__ be0,
                                              const float* __restrict__ B1,
                                              float* __restrict__ be1,
                                              float* __restrict__ xs1) {
    const int t = blockIdx.x;
    const int tid = threadIdx.x;
    __shared__ float xn[BATCH][HID];
    __shared__ float sc[BATCH];
    __shared__ float psum[BATCH][16];
    for (int idx = tid; idx < BATCH * HID; idx += 256) {
        int b = idx >> 9, k = idx & 511;
        xn[b][k] = be0[(t * BATCH + b) * HID + k];
    }
    __syncthreads();
    {
        int b = tid >> 4, l = tid & 15;
        float ss = 0.f;
        for (int k = l; k < HID; k += 16) { float v = xn[b][k]; ss += v * v; }
        psum[b][l] = ss;
    }
    __syncthreads();
    if (tid < BATCH) {
        float ss = 0.f;
        #pragma unroll
        for (int l = 0; l < 16; ++l) ss += psum[tid][l];
        float s = fmaxf(sqrtf(ss), 1e-6f);
        sc[tid] = s;
        xs1[t * BATCH + tid] = s;
    }
    __syncthreads();
    for (int idx = tid; idx < BATCH * HID; idx += 256) {
        int b = idx >> 9, k = idx & 511;
        float v = xn[b][k] / sc[b];
        xn[b][k] = fminf(fmaxf(v, -1.f), 1.f);
    }
    __syncthreads();
    for (int j = tid; j < HID; j += 256) {
        float acc[BATCH];
        #pragma unroll
        for (int b = 0; b < BATCH; ++b) acc[b] = 0.f;
        const float* brow = B1 + j * HID;
        for (int k = 0; k < HID; k += 4) {
            float4 w = *(const float4*)(brow + k);
            #pragma unroll
            for (int b = 0; b < BATCH; ++b) {
                float4 xv = *(const float4*)(&xn[b][k]);
                acc[b] += w.x * xv.x + w.y * xv.y + w.z * xv.z + w.w * xv.w;
            }
        }
        #pragma unroll
        for (int b = 0; b < BATCH; ++b)
            be1[(t * BATCH + b) * HID + j] = acc[b];
    }
}

// K3: sequential recurrence. 16 blocks/chain x 4 waves; each wave owns 8
// columns; weights register-resident (128 VGPR/lane, 512-VGPR budget);
// all cross-block data via coherence-point (sc0 sc1) ops; no fences.
__global__ __launch_bounds__(256, 1) void k3_wave(
    const float* __restrict__ be0, const float* __restrict__ be1,
    const float* __restrict__ xs1,
    const float* __restrict__ C1, const float* __restrict__ W1,
    const float* __restrict__ a1, const float* __restrict__ tau,
    const float* __restrict__ gam,
    float* __restrict__ h1s,
    float* h_buf, float* err_buf, int* flags)
{
    const int chain = blockIdx.x & 15;
    const int slice = blockIdx.x >> 4;        // 0..15
    const int tid = threadIdx.x;
    const int w = tid >> 6;                   // wave in block 0..3
    const int lane = tid & 63;
    const int ks = lane & 7;                  // k-group within column
    const int colw = lane >> 3;               // column within wave 0..7
    const int gw = slice * 4 + w;             // global wave id 0..63
    const int j = slice * 32 + w * 8 + colw;  // output column 0..511
    const bool lead = (ks == 0);

    // 32 float4 = 128 VGPRs of weights, loaded once, register-resident
    float4 wC[16], wW[16];
    {
        const float4* c4 = (const float4*)(C1 + (size_t)j * HID);
        const float4* w4 = (const float4*)(W1 + (size_t)j * HID);
        #pragma unroll
        for (int i = 0; i < 16; ++i) { wC[i] = c4[ks + 8 * i]; wW[i] = w4[ks + 8 * i]; }
    }
    const float tauv = tau[0], gamv = gam[0];
    const float siga = fast_sigmoid(a1[j]);

    float* hb = h_buf + chain * HID;
    float* eb = err_buf + chain * HID;
    int* flg = flags + chain * NWAVE;
    const float* hbase = hb + ks * 4;   // lane's base for chunked loads
    const float* ebase = eb + ks * 4;

    float hj = 0.f;
    float cur_be0 = 0.f, cur_be1 = 0.f;
    if (lead) {
        cur_be0 = __builtin_nontemporal_load(&be0[(size_t)chain * HID + j]);
        cur_be1 = __builtin_nontemporal_load(&be1[(size_t)chain * HID + j]);
    }
    float cur_xs = __builtin_nontemporal_load(&xs1[chain]);

    for (int t = 0; t < T_LEN; ++t) {
        // prefetch next step's streams (normal cached loads, off critical path)
        float nxt_be0 = 0.f, nxt_be1 = 0.f, nxt_xs = 0.f;
        if (t + 1 < T_LEN) {
            const size_t nrow = (size_t)((t + 1) * BATCH + chain) * HID;
            if (lead) {
                nxt_be0 = __builtin_nontemporal_load(&be0[nrow + j]);
                nxt_be1 = __builtin_nontemporal_load(&be1[nrow + j]);
            }
            nxt_xs = __builtin_nontemporal_load(&xs1[(t + 1) * BATCH + chain]);
        }

        // ---- wait: h(t) published by all 64 waves (token 2t) ----
        {
            const int tok = 2 * t;
            while (true) {
                int v = __hip_atomic_load(&flg[lane], __ATOMIC_RELAXED,
                                          __HIP_MEMORY_SCOPE_AGENT);
                if (__all(v >= tok)) break;
                __builtin_amdgcn_s_sleep(1);
            }
        }

        // ---- phase 1: dp = (h @ C1^T)[j], publish err ----
        float4 hv[16];
        llc_load16(hbase, hv);
        float dp = 0.f;
        #pragma unroll
        for (int i = 0; i < 16; ++i)
            dp += wC[i].x * hv[i].x + wC[i].y * hv[i].y
                + wC[i].z * hv[i].z + wC[i].w * hv[i].w;
        dp += __shfl_down(dp, 4, 8);
        dp += __shfl_down(dp, 2, 8);
        dp += __shfl_down(dp, 1, 8);
        if (lead) {
            float e = cur_be0 - fast_tanh(dp) * cur_xs;
            llc_store_f32(&eb[j], e);
        }
        vm_drain();                      // err stores at coherence point
        if (lane == 0)
            __hip_atomic_store(&flg[gw], 2 * t + 1, __ATOMIC_RELAXED,
                               __HIP_MEMORY_SCOPE_AGENT);

        // ---- wait: err(t) published by all 64 waves (token 2t+1) ----
        {
            const int tok = 2 * t + 1;
            while (true) {
                int v = __hip_atomic_load(&flg[lane], __ATOMIC_RELAXED,
                                          __HIP_MEMORY_SCOPE_AGENT);
                if (__all(v >= tok)) break;
                __builtin_amdgcn_s_sleep(1);
            }
        }

        // ---- phase 2: ssq from loaded err (8x dup => /8), ee = err@W1^T ----
        float4 ev[16];
        llc_load16(ebase, ev);
        float ee = 0.f, sq = 0.f;
        #pragma unroll
        for (int i = 0; i < 16; ++i) {
            ee += wW[i].x * ev[i].x + wW[i].y * ev[i].y
                + wW[i].z * ev[i].z + wW[i].w * ev[i].w;
            sq += ev[i].x * ev[i].x + ev[i].y * ev[i].y
                + ev[i].z * ev[i].z + ev[i].w * ev[i].w;
        }
        #pragma unroll
        for (int off = 32; off > 0; off >>= 1) sq += __shfl_down(sq, off, 64);
        float ssT = __shfl(sq, 0, 64) * 0.125f;
        ee += __shfl_down(ee, 4, 8);
        ee += __shfl_down(ee, 2, 8);
        ee += __shfl_down(ee, 1, 8);
        if (lead) {
            float rel = fminf(sqrtf(ssT) / cur_xs, 4.0f);
            float s = fast_sigmoid((rel - tauv) / gamv);
            float input_h = hj * 0.2f + cur_be1 * 0.6f + ee * s * 0.2f;
            float g = s * siga;
            hj = hj * (1.f - g) + fast_tanh(input_h) * g;
            llc_store_f32(&hb[j], hj);
            __builtin_nontemporal_store(hj, &h1s[(size_t)(t * BATCH + chain) * HID + j]);
        }
        vm_drain();                      // h stores at coherence point
        if (lane == 0)
            __hip_atomic_store(&flg[gw], 2 * t + 2, __ATOMIC_RELAXED,
                               __HIP_MEMORY_SCOPE_AGENT);

        cur_be0 = nxt_be0; cur_be1 = nxt_be1; cur_xs = nxt_xs;
    }
}

// K4: head matmul out[b,t,c] = [h1 || be1] @ head_w^T + head_b
__global__ __launch_bounds__(1024) void k4_head(const float* __restrict__ h1s,
                                                const float* __restrict__ be1,
                                                const float* __restrict__ head_w,
                                                const float* __restrict__ head_b,
                                                float* __restrict__ out) {
    const int t = blockIdx.x;
    const int tid = threadIdx.x;
    const int c = tid >> 4;
    const int b = tid & 15;
    const float* hw = head_w + c * (2 * HID);
    const float* x1 = h1s + (size_t)(t * BATCH + b) * HID;
    const float* x2 = be1 + (size_t)(t * BATCH + b) * HID;
    float acc0 = head_b[c], acc1 = 0.f;
    for (int k = 0; k < HID; k += 4) {
        float4 w = *(const float4*)(hw + k);
        float4 xv = *(const float4*)(x1 + k);
        acc0 += w.x * xv.x + w.y * xv.y + w.z * xv.z + w.w * xv.w;
    }
    for (int k = 0; k < HID; k += 4) {
        float4 w = *(const float4*)(hw + HID + k);
        float4 xv = *(const float4*)(x2 + k);
        acc1 += w.x * xv.x + w.y * xv.y + w.z * xv.z + w.w * xv.w;
    }
    out[b * (T_LEN * NCLS) + t * NCLS + c] = acc0 + acc1;
}

extern "C" void kernel_launch(void* const* d_in, const int* in_sizes, int n_in,
                              void* d_out, int out_size, void* d_ws, size_t ws_size,
                              hipStream_t stream) {
    const float* feats  = (const float*)d_in[0];
    const float* B0     = (const float*)d_in[2];
    const float* C1     = (const float*)d_in[7];
    const float* B1     = (const float*)d_in[8];
    const float* W1     = (const float*)d_in[9];
    const float* a1     = (const float*)d_in[10];
    const float* tau1   = (const float*)d_in[11];
    const float* gam1   = (const float*)d_in[12];
    const float* head_w = (const float*)d_in[13];
    const float* head_b = (const float*)d_in[14];
    float* out = (float*)d_out;

    float* be0   = (float*)d_ws;                          // T*B*HID
    float* be1   = be0 + (size_t)T_LEN * BATCH * HID;     // T*B*HID
    float* xs1   = be1 + (size_t)T_LEN * BATCH * HID;     // T*B
    float* h1s   = xs1 + (size_t)T_LEN * BATCH;           // T*B*HID
    float* h_buf = h1s + (size_t)T_LEN * BATCH * HID;     // B*HID
    float* ebuf  = h_buf + (size_t)BATCH * HID;           // B*HID
    int*   flags = (int*)(ebuf + (size_t)BATCH * HID);    // B*64

    hipLaunchKernelGGL(k0_init, dim3(32), dim3(256), 0, stream, h_buf, flags);
    hipLaunchKernelGGL(k1_be0, dim3(T_LEN), dim3(256), 0, stream, feats, B0, be0);
    hipLaunchKernelGGL(k2_be1, dim3(T_LEN), dim3(256), 0, stream, be0, B1, be1, xs1);
    hipLaunchKernelGGL(k3_wave, dim3(BATCH * SL), dim3(256), 0, stream,
                       be0, be1, xs1, C1, W1, a1, tau1, gam1, h1s,
                       h_buf, ebuf, flags);
    hipLaunchKernelGGL(k4_head, dim3(T_LEN), dim3(1024), 0, stream,
                       h1s, be1, head_w, head_b, out);
}

// Round 6
// 6276.243 us; speedup vs baseline: 12.6489x; 2.0280x over previous
//
#include <hip/hip_runtime.h>
#include <math.h>

#define T_LEN 1000
#define BATCH 16
#define MEL   80
#define HID   512
#define NCLS  64
#define SL    16       // column slices (blocks) per chain
#define CNT_STRIDE 32  // ints per chain counter line (128 B padding)

__device__ __forceinline__ float fast_tanh(float x) {
    float e = __expf(2.0f * x);
    return 1.0f - 2.0f / (e + 1.0f);
}
__device__ __forceinline__ float fast_sigmoid(float x) {
    return 1.0f / (1.0f + __expf(-x));
}

// ---- cache-bypassing (coherence-point) memory ops: sc0 sc1 => skip L1+L2,
// coherence point = die-level Infinity Cache (device-coherent). No fences.
// Also used for weights: asm-defined outputs cannot be rematerialized by the
// compiler, forcing true VGPR residency for the 2x16 float4 weight arrays.
__device__ __forceinline__ void llc_load16(const float* base, float4 (&r)[16]) {
    asm volatile(
        "global_load_dwordx4 %0, %16, off sc0 sc1\n\t"
        "global_load_dwordx4 %1, %16, off offset:128 sc0 sc1\n\t"
        "global_load_dwordx4 %2, %16, off offset:256 sc0 sc1\n\t"
        "global_load_dwordx4 %3, %16, off offset:384 sc0 sc1\n\t"
        "global_load_dwordx4 %4, %16, off offset:512 sc0 sc1\n\t"
        "global_load_dwordx4 %5, %16, off offset:640 sc0 sc1\n\t"
        "global_load_dwordx4 %6, %16, off offset:768 sc0 sc1\n\t"
        "global_load_dwordx4 %7, %16, off offset:896 sc0 sc1\n\t"
        "global_load_dwordx4 %8, %16, off offset:1024 sc0 sc1\n\t"
        "global_load_dwordx4 %9, %16, off offset:1152 sc0 sc1\n\t"
        "global_load_dwordx4 %10, %16, off offset:1280 sc0 sc1\n\t"
        "global_load_dwordx4 %11, %16, off offset:1408 sc0 sc1\n\t"
        "global_load_dwordx4 %12, %16, off offset:1536 sc0 sc1\n\t"
        "global_load_dwordx4 %13, %16, off offset:1664 sc0 sc1\n\t"
        "global_load_dwordx4 %14, %16, off offset:1792 sc0 sc1\n\t"
        "global_load_dwordx4 %15, %16, off offset:1920 sc0 sc1\n\t"
        "s_waitcnt vmcnt(0)"
        : "=&v"(r[0]), "=&v"(r[1]), "=&v"(r[2]), "=&v"(r[3]),
          "=&v"(r[4]), "=&v"(r[5]), "=&v"(r[6]), "=&v"(r[7]),
          "=&v"(r[8]), "=&v"(r[9]), "=&v"(r[10]), "=&v"(r[11]),
          "=&v"(r[12]), "=&v"(r[13]), "=&v"(r[14]), "=&v"(r[15])
        : "v"(base)
        : "memory");
}
__device__ __forceinline__ void llc_store_f32(float* p, float v) {
    asm volatile("global_store_dword %0, %1, off sc0 sc1" :: "v"(p), "v"(v) : "memory");
}
__device__ __forceinline__ void vm_drain() {
    asm volatile("s_waitcnt vmcnt(0)" ::: "memory");
}

// K0: zero inter-block state
__global__ void k0_init(float* h_buf, int* cnt) {
    int i = blockIdx.x * 256 + threadIdx.x;
    if (i < BATCH * HID) h_buf[i] = 0.f;
    if (i < BATCH * CNT_STRIDE) cnt[i] = 0;
}

// K1: per t: x_norm0 from feats, be0 = x_norm0 @ B0^T
__global__ __launch_bounds__(256) void k1_be0(const float* __restrict__ feats,
                                              const float* __restrict__ B0,
                                              float* __restrict__ be0) {
    const int t = blockIdx.x;
    const int tid = threadIdx.x;
    __shared__ float xf[BATCH][MEL];
    __shared__ float sc[BATCH];
    for (int idx = tid; idx < BATCH * MEL; idx += 256) {
        int b = idx / MEL, m = idx % MEL;
        xf[b][m] = feats[b * (T_LEN * MEL) + t * MEL + m];
    }
    __syncthreads();
    if (tid < BATCH) {
        float ss = 0.f;
        for (int m = 0; m < MEL; ++m) { float v = xf[tid][m]; ss += v * v; }
        sc[tid] = fmaxf(sqrtf(ss), 1e-6f);
    }
    __syncthreads();
    for (int idx = tid; idx < BATCH * MEL; idx += 256) {
        int b = idx / MEL, m = idx % MEL;
        float v = xf[b][m] / sc[b];
        xf[b][m] = fminf(fmaxf(v, -1.f), 1.f);
    }
    __syncthreads();
    for (int j = tid; j < HID; j += 256) {
        float acc[BATCH];
        #pragma unroll
        for (int b = 0; b < BATCH; ++b) acc[b] = 0.f;
        const float* brow = B0 + j * MEL;
        for (int k = 0; k < MEL; k += 4) {
            float4 w = *(const float4*)(brow + k);
            #pragma unroll
            for (int b = 0; b < BATCH; ++b) {
                float4 xv = *(const float4*)(&xf[b][k]);
                acc[b] += w.x * xv.x + w.y * xv.y + w.z * xv.z + w.w * xv.w;
            }
        }
        #pragma unroll
        for (int b = 0; b < BATCH; ++b)
            be0[(t * BATCH + b) * HID + j] = acc[b];
    }
}

// K2: per t: x_norm1 from be0, be1 = x_norm1 @ B1^T, store xs1
__global__ __launch_bounds__(256) void k2_be1(const float* __restrict__ be0,
                                              const float* __restrict__ B1,
                                              float* __restrict__ be1,
                                              float* __restrict__ xs1) {
    const int t = blockIdx.x;
    const int tid = threadIdx.x;
    __shared__ float xn[BATCH][HID];
    __shared__ float sc[BATCH];
    __shared__ float psum[BATCH][16];
    for (int idx = tid; idx < BATCH * HID; idx += 256) {
        int b = idx >> 9, k = idx & 511;
        xn[b][k] = be0[(t * BATCH + b) * HID + k];
    }
    __syncthreads();
    {
        int b = tid >> 4, l = tid & 15;
        float ss = 0.f;
        for (int k = l; k < HID; k += 16) { float v = xn[b][k]; ss += v * v; }
        psum[b][l] = ss;
    }
    __syncthreads();
    if (tid < BATCH) {
        float ss = 0.f;
        #pragma unroll
        for (int l = 0; l < 16; ++l) ss += psum[tid][l];
        float s = fmaxf(sqrtf(ss), 1e-6f);
        sc[tid] = s;
        xs1[t * BATCH + tid] = s;
    }
    __syncthreads();
    for (int idx = tid; idx < BATCH * HID; idx += 256) {
        int b = idx >> 9, k = idx & 511;
        float v = xn[b][k] / sc[b];
        xn[b][k] = fminf(fmaxf(v, -1.f), 1.f);
    }
    __syncthreads();
    for (int j = tid; j < HID; j += 256) {
        float acc[BATCH];
        #pragma unroll
        for (int b = 0; b < BATCH; ++b) acc[b] = 0.f;
        const float* brow = B1 + j * HID;
        for (int k = 0; k < HID; k += 4) {
            float4 w = *(const float4*)(brow + k);
            #pragma unroll
            for (int b = 0; b < BATCH; ++b) {
                float4 xv = *(const float4*)(&xn[b][k]);
                acc[b] += w.x * xv.x + w.y * xv.y + w.z * xv.z + w.w * xv.w;
            }
        }
        #pragma unroll
        for (int b = 0; b < BATCH; ++b)
            be1[(t * BATCH + b) * HID + j] = acc[b];
    }
}

// K3: sequential recurrence. 16 blocks/chain x 4 waves; each wave owns 8
// columns; weights asm-loaded (non-rematerializable => VGPR-resident);
// single monotonic per-chain counter barrier.
__global__ __launch_bounds__(256, 1) void k3_wave(
    const float* __restrict__ be0, const float* __restrict__ be1,
    const float* __restrict__ xs1,
    const float* __restrict__ C1, const float* __restrict__ W1,
    const float* __restrict__ a1, const float* __restrict__ tau,
    const float* __restrict__ gam,
    float* __restrict__ h1s,
    float* h_buf, float* err_buf, int* cnt_arr)
{
    const int chain = blockIdx.x & 15;
    const int slice = blockIdx.x >> 4;        // 0..15
    const int tid = threadIdx.x;
    const int w = tid >> 6;                   // wave in block 0..3
    const int lane = tid & 63;
    const int ks = lane & 7;                  // k-group within column
    const int colw = lane >> 3;               // column within wave 0..7
    const int j = slice * 32 + w * 8 + colw;  // output column 0..511
    const bool lead = (ks == 0);

    // 32 float4 = 128 VGPRs of weights, asm-defined (cannot be rematerialized)
    float4 wC[16], wW[16];
    llc_load16(C1 + (size_t)j * HID + ks * 4, wC);
    llc_load16(W1 + (size_t)j * HID + ks * 4, wW);

    const float tauv = tau[0], gamv = gam[0];
    const float siga = fast_sigmoid(a1[j]);

    float* hb = h_buf + chain * HID;
    float* eb = err_buf + chain * HID;
    int* cnt = cnt_arr + chain * CNT_STRIDE;
    const float* hbase = hb + ks * 4;
    const float* ebase = eb + ks * 4;

    float hj = 0.f;
    float cur_be0 = 0.f, cur_be1 = 0.f;
    if (lead) {
        cur_be0 = __builtin_nontemporal_load(&be0[(size_t)chain * HID + j]);
        cur_be1 = __builtin_nontemporal_load(&be1[(size_t)chain * HID + j]);
    }
    float cur_xs = __builtin_nontemporal_load(&xs1[chain]);

    for (int t = 0; t < T_LEN; ++t) {
        // prefetch next step's streams (overlaps the polls below)
        float nxt_be0 = 0.f, nxt_be1 = 0.f, nxt_xs = 0.f;
        if (t + 1 < T_LEN) {
            const size_t nrow = (size_t)((t + 1) * BATCH + chain) * HID;
            if (lead) {
                nxt_be0 = __builtin_nontemporal_load(&be0[nrow + j]);
                nxt_be1 = __builtin_nontemporal_load(&be1[nrow + j]);
            }
            nxt_xs = __builtin_nontemporal_load(&xs1[(t + 1) * BATCH + chain]);
        }

        // ---- wait: h(t) ready  (cnt >= 32t) ----
        {
            const int tok = 32 * t;
            while (__hip_atomic_load(cnt, __ATOMIC_RELAXED,
                                     __HIP_MEMORY_SCOPE_AGENT) < tok)
                __builtin_amdgcn_s_sleep(1);
        }

        // ---- phase 1: dp = (h @ C1^T)[j], publish err ----
        float4 hv[16];
        llc_load16(hbase, hv);
        float dp = 0.f;
        #pragma unroll
        for (int i = 0; i < 16; ++i)
            dp += wC[i].x * hv[i].x + wC[i].y * hv[i].y
                + wC[i].z * hv[i].z + wC[i].w * hv[i].w;
        dp += __shfl_down(dp, 4, 8);
        dp += __shfl_down(dp, 2, 8);
        dp += __shfl_down(dp, 1, 8);
        if (lead) {
            float e = cur_be0 - fast_tanh(dp) * cur_xs;
            llc_store_f32(&eb[j], e);
        }
        vm_drain();                      // err stores at coherence point
        __syncthreads();                 // all 4 waves of block drained
        if (tid == 0) atomicAdd(cnt, 1); // fire-and-forget arrival

        // ---- wait: err(t) ready  (cnt >= 32t + 16) ----
        {
            const int tok = 32 * t + 16;
            while (__hip_atomic_load(cnt, __ATOMIC_RELAXED,
                                     __HIP_MEMORY_SCOPE_AGENT) < tok)
                __builtin_amdgcn_s_sleep(1);
        }

        // ---- phase 2: ssq from loaded err (8x dup => /8), ee = err@W1^T ----
        float4 ev[16];
        llc_load16(ebase, ev);
        float ee = 0.f, sq = 0.f;
        #pragma unroll
        for (int i = 0; i < 16; ++i) {
            ee += wW[i].x * ev[i].x + wW[i].y * ev[i].y
                + wW[i].z * ev[i].z + wW[i].w * ev[i].w;
            sq += ev[i].x * ev[i].x + ev[i].y * ev[i].y
                + ev[i].z * ev[i].z + ev[i].w * ev[i].w;
        }
        #pragma unroll
        for (int off = 32; off > 0; off >>= 1) sq += __shfl_down(sq, off, 64);
        float ssT = __shfl(sq, 0, 64) * 0.125f;
        ee += __shfl_down(ee, 4, 8);
        ee += __shfl_down(ee, 2, 8);
        ee += __shfl_down(ee, 1, 8);
        if (lead) {
            float rel = fminf(sqrtf(ssT) / cur_xs, 4.0f);
            float s = fast_sigmoid((rel - tauv) / gamv);
            float input_h = hj * 0.2f + cur_be1 * 0.6f + ee * s * 0.2f;
            float g = s * siga;
            hj = hj * (1.f - g) + fast_tanh(input_h) * g;
            llc_store_f32(&hb[j], hj);
        }
        vm_drain();                      // h stores at coherence point
        __syncthreads();
        if (tid == 0) atomicAdd(cnt, 1);
        // h1s output store off the critical path (completes during next poll)
        if (lead)
            __builtin_nontemporal_store(hj, &h1s[(size_t)(t * BATCH + chain) * HID + j]);

        cur_be0 = nxt_be0; cur_be1 = nxt_be1; cur_xs = nxt_xs;
    }
}

// K4: head matmul out[b,t,c] = [h1 || be1] @ head_w^T + head_b
__global__ __launch_bounds__(1024) void k4_head(const float* __restrict__ h1s,
                                                const float* __restrict__ be1,
                                                const float* __restrict__ head_w,
                                                const float* __restrict__ head_b,
                                                float* __restrict__ out) {
    const int t = blockIdx.x;
    const int tid = threadIdx.x;
    const int c = tid >> 4;
    const int b = tid & 15;
    const float* hw = head_w + c * (2 * HID);
    const float* x1 = h1s + (size_t)(t * BATCH + b) * HID;
    const float* x2 = be1 + (size_t)(t * BATCH + b) * HID;
    float acc0 = head_b[c], acc1 = 0.f;
    for (int k = 0; k < HID; k += 4) {
        float4 w = *(const float4*)(hw + k);
        float4 xv = *(const float4*)(x1 + k);
        acc0 += w.x * xv.x + w.y * xv.y + w.z * xv.z + w.w * xv.w;
    }
    for (int k = 0; k < HID; k += 4) {
        float4 w = *(const float4*)(hw + HID + k);
        float4 xv = *(const float4*)(x2 + k);
        acc1 += w.x * xv.x + w.y * xv.y + w.z * xv.z + w.w * xv.w;
    }
    out[b * (T_LEN * NCLS) + t * NCLS + c] = acc0 + acc1;
}

extern "C" void kernel_launch(void* const* d_in, const int* in_sizes, int n_in,
                              void* d_out, int out_size, void* d_ws, size_t ws_size,
                              hipStream_t stream) {
    const float* feats  = (const float*)d_in[0];
    const float* B0     = (const float*)d_in[2];
    const float* C1     = (const float*)d_in[7];
    const float* B1     = (const float*)d_in[8];
    const float* W1     = (const float*)d_in[9];
    const float* a1     = (const float*)d_in[10];
    const float* tau1   = (const float*)d_in[11];
    const float* gam1   = (const float*)d_in[12];
    const float* head_w = (const float*)d_in[13];
    const float* head_b = (const float*)d_in[14];
    float* out = (float*)d_out;

    float* be0   = (float*)d_ws;                          // T*B*HID
    float* be1   = be0 + (size_t)T_LEN * BATCH * HID;     // T*B*HID
    float* xs1   = be1 + (size_t)T_LEN * BATCH * HID;     // T*B
    float* h1s   = xs1 + (size_t)T_LEN * BATCH;           // T*B*HID
    float* h_buf = h1s + (size_t)T_LEN * BATCH * HID;     // B*HID
    float* ebuf  = h_buf + (size_t)BATCH * HID;           // B*HID
    int*   cnt   = (int*)(ebuf + (size_t)BATCH * HID);    // B*32

    hipLaunchKernelGGL(k0_init, dim3(32), dim3(256), 0, stream, h_buf, cnt);
    hipLaunchKernelGGL(k1_be0, dim3(T_LEN), dim3(256), 0, stream, feats, B0, be0);
    hipLaunchKernelGGL(k2_be1, dim3(T_LEN), dim3(256), 0, stream, be0, B1, be1, xs1);
    hipLaunchKernelGGL(k3_wave, dim3(BATCH * SL), dim3(256), 0, stream,
                       be0, be1, xs1, C1, W1, a1, tau1, gam1, h1s,
                       h_buf, ebuf, cnt);
    hipLaunchKernelGGL(k4_head, dim3(T_LEN), dim3(1024), 0, stream,
                       h1s, be1, head_w, head_b, out);
}